// Round 3
// baseline (484.466 us; speedup 1.0000x reference)
//
#include <hip/hip_runtime.h>
#include <stdint.h>

// Problem constants (B=256, L=2048, H=64, TE=64)
#define NB 256
#define NL 2048

typedef __attribute__((ext_vector_type(8))) short short8;
typedef __attribute__((ext_vector_type(4))) float f32x4;
#define MFMA16(a,b,c) __builtin_amdgcn_mfma_f32_16x16x32_bf16(a,b,c,0,0,0)

// ---------- bf16 helpers ----------
// R11: HW packed cvt proven safe. R15: lgkm-only barriers (neutral alone).
// R16: inp bf16 intermediate, gates moved into scan (371->334).
// R17: prep eliminated — te1/x3 fragments computed in-register inside the
//      scan; inp never touches global memory. 3-barrier/segment pipeline:
//      alpha {out(i-1) | gates(i)}  beta {scanAB(i) | tencGEMM(i+1)}
//      gamma {carry(i) | inpGEMM(i+1) | t/x prefetch(i+2)}.
static __device__ __forceinline__ unsigned short f2bf(float f) {
    union { float f; uint32_t u; } v; v.f = f;
    uint32_t u = v.u;
    uint32_t r = u + 0x7fffu + ((u >> 16) & 1u);
    return (unsigned short)(r >> 16);
}
static __device__ __forceinline__ float bflo(uint32_t u) {
    union { uint32_t u; float f; } v; v.u = u << 16; return v.f;
}
static __device__ __forceinline__ float bfhi(uint32_t u) {
    union { uint32_t u; float f; } v; v.u = u & 0xffff0000u; return v.f;
}
#if __has_builtin(__builtin_amdgcn_cvt_pk_bf16_f32)
typedef __attribute__((ext_vector_type(2))) __bf16 bf16x2_t;
static __device__ __forceinline__ uint32_t pk2(float lo, float hi) {
    union { bf16x2_t v; uint32_t u; } c;
    c.v = __builtin_amdgcn_cvt_pk_bf16_f32(lo, hi);
    return c.u;
}
static __device__ __forceinline__ unsigned short bf1(float v) {
    union { bf16x2_t v; uint32_t u; } c;
    c.v = __builtin_amdgcn_cvt_pk_bf16_f32(v, v);
    return (unsigned short)(c.u & 0xffffu);
}
#else
static __device__ __forceinline__ uint32_t pk2(float lo, float hi) {
    return ((uint32_t)f2bf(hi) << 16) | (uint32_t)f2bf(lo);
}
static __device__ __forceinline__ unsigned short bf1(float v) { return f2bf(v); }
#endif
static __device__ __forceinline__ short8 frag8(const float* p) {
    short8 r;
#pragma unroll
    for (int j = 0; j < 8; ++j) r[j] = (short)f2bf(p[j]);
    return r;
}

// LDS-only barrier: global stores/loads stay in flight across it.
static __device__ __forceinline__ void barrier_lds() {
    asm volatile("s_waitcnt lgkmcnt(0)" ::: "memory");
    __builtin_amdgcn_s_barrier();
}

// =====================================================================
// kernel 1: fused inp-gen + gates + chunked scan.
// 512 thr = 8 waves; lane = h (64), wave q owns 16-l chunk of the
// 128-l segment. All GEMM fragment orders/roundings identical to the
// old prep kernel -> bitwise-identical h outputs.
// =====================================================================
#define SSTR 129

__global__ __launch_bounds__(512, 2) void scan_fused(
    const float* __restrict__ x, const float* __restrict__ t,
    const float* __restrict__ mtok,
    const float* __restrict__ te_w1, const float* __restrict__ te_b1,
    const float* __restrict__ te_w2, const float* __restrict__ te_b2,
    const float* __restrict__ fpw, const float* __restrict__ fpb,
    const float* __restrict__ bpw, const float* __restrict__ bpb,
    const float* __restrict__ fwz, const float* __restrict__ fbz,
    const float* __restrict__ fwh, const float* __restrict__ fbh,
    const float* __restrict__ bwz, const float* __restrict__ bbz,
    const float* __restrict__ bwh, const float* __restrict__ bbh,
    int b0,
    unsigned short* __restrict__ hf, unsigned short* __restrict__ hb)
{
    __shared__ __align__(16) unsigned short s_tenc[128*72];  // 18432 B
    __shared__ __align__(16) unsigned short s_inp[128*72];   // 18432 B
    __shared__ uint32_t s_seg[64*SSTR];                      // 33024 B
    __shared__ float s_A[8][65], s_B[8][65];                 //  4160 B
    __shared__ float s_H[64];                                //   256 B

    const int rl  = blockIdx.x >> 1;
    const int dir = blockIdx.x & 1;
    const int tid = threadIdx.x;
    const int h   = tid & 63;     // lane
    const int q   = tid >> 6;     // wave 0..7
    const int lq  = h >> 4;
    const int ln  = h & 15;

    const int gx = (b0 + rl) << 11;     // global l base for this b
    unsigned short* out = (dir ? hb : hf) + (size_t)rl * NL * 64;

    // ---- weights (persistent regs) ----
    // te1-gen constants for this lane's k-slots (k = lq*8 + ks*32 + j)
    float w1v[16], b1v[16];
#pragma unroll
    for (int ks = 0; ks < 2; ++ks)
#pragma unroll
        for (int j = 0; j < 8; ++j) {
            const int k = lq*8 + ks*32 + j;
            w1v[ks*8+j] = te_w1[k];
            b1v[ks*8+j] = te_b1[k];
        }
    short8 bte[4][2];
    float bite[4];
#pragma unroll
    for (int nt = 0; nt < 4; ++nt) {
        const float* row = te_w2 + (nt*16 + ln)*64;
#pragma unroll
        for (int ks = 0; ks < 2; ++ks) bte[nt][ks] = frag8(row + lq*8 + ks*32);
        bite[nt] = te_b2[nt*16 + ln];
    }
    const float* PW = dir ? bpw : fpw;
    const float* PB = dir ? bpb : fpb;
    short8 bpj[4][3];
    float bipj[4];
#pragma unroll
    for (int nt = 0; nt < 4; ++nt) {
        const float* row = PW + (nt*16 + ln)*67;
#pragma unroll
        for (int ks = 0; ks < 2; ++ks) {
            float tmp[8];
#pragma unroll
            for (int j = 0; j < 8; ++j) tmp[j] = row[3 + lq*8 + ks*32 + j];
            bpj[nt][ks] = frag8(tmp);
        }
        {
            float tmp[8];
#pragma unroll
            for (int j = 0; j < 8; ++j) tmp[j] = (lq == 0 && j < 3) ? row[j] : 0.f;
            bpj[nt][2] = frag8(tmp);
        }
        bipj[nt] = PB[nt*16 + ln];
    }
    const float* WZ = dir ? bwz : fwz;
    const float* WH = dir ? bwh : fwh;
    const float* BZ = dir ? bbz : fbz;
    const float* BH = dir ? bbh : fbh;
    short8 bz[4][2], bh[4][2];
    float biz[4], bih[4];
#pragma unroll
    for (int nt = 0; nt < 4; ++nt) {
        const float* rz = WZ + (nt*16 + ln)*64;
        const float* rh = WH + (nt*16 + ln)*64;
#pragma unroll
        for (int ks = 0; ks < 2; ++ks) {
            bz[nt][ks] = frag8(rz + lq*8 + ks*32);
            bh[nt][ks] = frag8(rh + lq*8 + ks*32);
        }
        biz[nt] = BZ[nt*16 + ln];
        bih[nt] = BH[nt*16 + ln];
    }
    const float mt0 = mtok[0], mt1 = mtok[1];

    // ---- phase lambdas ----
    auto G1 = [&](float tv) {   // in-reg te1 + tenc GEMM -> s_tenc
        short8 a[2];
#pragma unroll
        for (int ks = 0; ks < 2; ++ks)
#pragma unroll
            for (int j = 0; j < 8; ++j) {
                const float v = fmaxf(fmaf(tv, w1v[ks*8+j], b1v[ks*8+j]), 0.f);
                a[ks][j] = (short)bf1(v);
            }
#pragma unroll
        for (int nt = 0; nt < 4; ++nt) {
            f32x4 c = {0.f, 0.f, 0.f, 0.f};
            c = MFMA16(a[0], bte[nt][0], c);
            c = MFMA16(a[1], bte[nt][1], c);
#pragma unroll
            for (int r = 0; r < 4; ++r)
                s_tenc[(q*16 + lq*4 + r)*72 + nt*16 + ln] = bf1(c[r] + bite[nt]);
        }
    };
    auto G2 = [&](float xx0, float xx1, float mc) {  // tenc + in-reg x3 -> s_inp
        const short8 a0 = *(const short8*)(s_tenc + (q*16+ln)*72 + lq*8);
        const short8 a1 = *(const short8*)(s_tenc + (q*16+ln)*72 + lq*8 + 32);
        short8 a2 = {0,0,0,0,0,0,0,0};
        if (lq == 0) {
            const float x0m = (mc == 0.f) ? mt0 : xx0;
            const float x1m = (mc == 0.f) ? mt1 : xx1;
            a2[0] = (short)bf1(x0m);
            a2[1] = (short)bf1(x1m);
            a2[2] = (short)bf1(mc);
        }
#pragma unroll
        for (int nt = 0; nt < 4; ++nt) {
            f32x4 c = {0.f, 0.f, 0.f, 0.f};
            c = MFMA16(a0, bpj[nt][0], c);
            c = MFMA16(a1, bpj[nt][1], c);
            c = MFMA16(a2, bpj[nt][2], c);
#pragma unroll
            for (int r = 0; r < 4; ++r)
                s_inp[(q*16 + lq*4 + r)*72 + nt*16 + ln] = bf1(c[r] + bipj[nt]);
        }
    };
    auto GATES = [&]() {        // s_inp -> gates -> s_seg (same math as R16)
        const short8 a0 = *(const short8*)(s_inp + (q*16+ln)*72 + lq*8);
        const short8 a1 = *(const short8*)(s_inp + (q*16+ln)*72 + lq*8 + 32);
#pragma unroll
        for (int nt = 0; nt < 4; ++nt) {
            f32x4 cz  = {0.f, 0.f, 0.f, 0.f};
            f32x4 ch2 = {0.f, 0.f, 0.f, 0.f};
            cz  = MFMA16(a0, bz[nt][0], cz);
            cz  = MFMA16(a1, bz[nt][1], cz);
            ch2 = MFMA16(a0, bh[nt][0], ch2);
            ch2 = MFMA16(a1, bh[nt][1], ch2);
#pragma unroll
            for (int r = 0; r < 4; ++r) {
                const float az = cz[r]  + biz[nt];
                const float ah = ch2[r] + bih[nt];
                const float z  = __builtin_amdgcn_rcpf(1.f + __expf(-az));
                const float cc = fminf(fmaxf(ah, -15.f), 15.f);
                const float e2 = __expf(2.f * cc);
                const float th = 1.f - 2.f * __builtin_amdgcn_rcpf(e2 + 1.f);
                s_seg[(nt*16 + ln)*SSTR + q*16 + lq*4 + r] = pk2(1.f - z, z * th);
            }
        }
    };

    if (tid < 64) s_H[tid] = 0.f;

    // ---- prologue: stage segment s0 ----
    const int s0 = dir ? 15 : 0;
    G1(t[gx + s0*128 + q*16 + ln]);
    barrier_lds();
    float xr0 = 0.f, xr1 = 0.f, xmc = 0.f;
    if (lq == 0) {
        const float* xp = x + (size_t)(gx + s0*128 + q*16 + ln)*3;
        xr0 = xp[0]; xr1 = xp[1]; xmc = xp[2];
    }
    G2(xr0, xr1, xmc);
    // prefetch for s(1)
    const int s1 = dir ? 14 : 1;
    float tvn = t[gx + s1*128 + q*16 + ln];
    if (lq == 0) {
        const float* xp = x + (size_t)(gx + s1*128 + q*16 + ln)*3;
        xr0 = xp[0]; xr1 = xp[1]; xmc = xp[2];
    }
    barrier_lds();

    uint32_t regs[16];
    int l0p = 0;

#pragma unroll 1
    for (int si = 0; si < 16; ++si) {
        const int s = dir ? (15 - si) : si;
        // ---- alpha: OUT(prev) + GATES(cur) ----
        if (si > 0) {
            float hv = s_A[q][h];     // Hin written in-place by carry
#pragma unroll
            for (int i = 0; i < 16; ++i) {
                const int g = q*16 + i;
                const int xx = dir ? (127 - g) : g;
                out[(size_t)(l0p + xx)*64 + h] = bf1(hv);
                hv = fmaf(bflo(regs[i]), hv, bfhi(regs[i]));
            }
        }
        GATES();
        barrier_lds();
        // ---- beta: scanAB(cur) + G1(next) ----
        {
            float A = 1.f, Bc = 0.f;
#pragma unroll
            for (int i = 0; i < 16; ++i) {
                const int g = q*16 + i;
                const int xx = dir ? (127 - g) : g;
                const uint32_t uab = s_seg[h*SSTR + xx];
                regs[i] = uab;
                Bc = fmaf(bflo(uab), Bc, bfhi(uab));
                A *= bflo(uab);
            }
            s_A[q][h] = A; s_B[q][h] = Bc;
        }
        if (si < 15) G1(tvn);
        barrier_lds();
        // ---- gamma: carry(cur) + G2(next) + prefetch(next-next) ----
        if (tid < 64) {
            float H = s_H[tid];
#pragma unroll
            for (int qq = 0; qq < 8; ++qq) {
                const float a = s_A[qq][tid], b = s_B[qq][tid];
                s_A[qq][tid] = H;          // in-place Hin
                H = fmaf(a, H, b);
            }
            s_H[tid] = H;
        }
        if (si < 15) {
            G2(xr0, xr1, xmc);
            if (si < 14) {
                const int s2 = dir ? (13 - si) : (si + 2);
                tvn = t[gx + s2*128 + q*16 + ln];
                if (lq == 0) {
                    const float* xp = x + (size_t)(gx + s2*128 + q*16 + ln)*3;
                    xr0 = xp[0]; xr1 = xp[1]; xmc = xp[2];
                }
            }
        }
        barrier_lds();
        l0p = s * 128;
    }
    // ---- epilogue: OUT(last) ----
    {
        float hv = s_A[q][h];
#pragma unroll
        for (int i = 0; i < 16; ++i) {
            const int g = q*16 + i;
            const int xx = dir ? (127 - g) : g;
            out[(size_t)(l0p + xx)*64 + h] = bf1(hv);
            hv = fmaf(bflo(regs[i]), hv, bfhi(regs[i]));
        }
    }
}

// =====================================================================
// kernel 2: MFMA head — unchanged from R15/R16.
// =====================================================================
__global__ __launch_bounds__(256, 3) void head_kernel(
    const float* __restrict__ x, const float* __restrict__ t,
    const float* __restrict__ te_w1, const float* __restrict__ te_b1,
    const float* __restrict__ te_w2, const float* __restrict__ te_b2,
    const unsigned short* __restrict__ hf, const unsigned short* __restrict__ hb,
    const float* __restrict__ w1, const float* __restrict__ b1,
    const float* __restrict__ w2, const float* __restrict__ b2,
    int b0,
    float* __restrict__ out)
{
    __shared__ __align__(16) unsigned short s_a[64*200];   // 25600 B
    __shared__ __align__(16) unsigned short s_te1[64*72];  //  9216 B
    __shared__ float s_part[4][64];                        //  1024 B
    __shared__ float s_mc[64];                             //   256 B

    const int tid = threadIdx.x;
    const int w   = tid >> 6;
    const int l   = tid & 63;
    const int lq  = l >> 4;
    const int ln  = l & 15;

    short8 bw1[2][6];
    float b1v[2], w2v[2];
#pragma unroll
    for (int p = 0; p < 2; ++p) {
        const int o = (2*w + p)*16 + ln;
        const float* row = w1 + o*192;
#pragma unroll
        for (int ks = 0; ks < 6; ++ks) bw1[p][ks] = frag8(row + lq*8 + ks*32);
        b1v[p] = b1[o];
        w2v[p] = w2[o];
    }
    short8 bte[2];
    {
        const float* row = te_w2 + (w*16 + ln)*64;
#pragma unroll
        for (int ks = 0; ks < 2; ++ks) bte[ks] = frag8(row + lq*8 + ks*32);
    }
    const float bias_te = te_b2[w*16 + ln];
    const float bias2 = b2[0];

    const int baseposl = blockIdx.x * 256;

    auto A = [&](int ch) {    // mc + te1 staging
        const int gbase = (b0 << 11) + baseposl + ch*64;
        if (tid < 64) s_mc[tid] = x[(size_t)(gbase + tid)*3 + 2];
        const int pos = tid & 63;
        const float tv = t[gbase + pos];
        const int k0 = (tid >> 6) * 16;
        uint32_t* dst = (uint32_t*)(s_te1 + pos*72 + k0);
#pragma unroll
        for (int kk = 0; kk < 16; kk += 2) {
            float v0 = fmaxf(fmaf(tv, te_w1[k0+kk],   te_b1[k0+kk]),   0.f);
            float v1 = fmaxf(fmaf(tv, te_w1[k0+kk+1], te_b1[k0+kk+1]), 0.f);
            dst[kk >> 1] = pk2(v0, v1);
        }
    };
    auto Bp = [&](int ch) {   // uint4 gather + tenc GEMM (disjoint s_a cols)
        const int chbase = baseposl + ch*64;
        const int ll0 = chbase & 2047;
        const int bl  = chbase >> 11;
        const size_t rowbase = (size_t)bl * NL * 64;
#pragma unroll
        for (int rep = 0; rep < 4; ++rep) {
            const int idx = rep*256 + tid;
            const int seg = idx >> 9;
            const int row = (idx >> 3) & 63;
            const int c   = idx & 7;
            const bool unm = s_mc[row] > 0.f;
            const uint4* src = (seg == 0)
                ? (const uint4*)(hf + rowbase + (size_t)(unm ? (ll0+row) : (NL-1))*64)
                : (const uint4*)(hb + rowbase + (size_t)(unm ? (ll0+row) : 0)*64);
            ((uint4*)s_a)[row*25 + seg*8 + c] = src[c];
        }
        const int o = w*16 + ln;
#pragma unroll
        for (int mt = 0; mt < 4; ++mt) {
            f32x4 c = {0.f, 0.f, 0.f, 0.f};
#pragma unroll
            for (int ks = 0; ks < 2; ++ks) {
                const short8 a = *(const short8*)(s_te1 + (mt*16+ln)*72 + lq*8 + ks*32);
                c = MFMA16(a, bte[ks], c);
            }
#pragma unroll
            for (int r = 0; r < 4; ++r) {
                const int m = mt*16 + lq*4 + r;
                s_a[m*200 + 128 + o] = bf1(c[r] + bias_te);
            }
        }
    };
    auto Cp = [&]() {         // GEMM1 + relu*w2 + quad shuffle-reduce
#pragma unroll
        for (int mt = 0; mt < 4; ++mt) {
            short8 af[6];
#pragma unroll
            for (int ks = 0; ks < 6; ++ks)
                af[ks] = *(const short8*)(s_a + (mt*16+ln)*200 + lq*8 + ks*32);
            float vs[4] = {0.f, 0.f, 0.f, 0.f};
#pragma unroll
            for (int p = 0; p < 2; ++p) {
                f32x4 c = {0.f, 0.f, 0.f, 0.f};
#pragma unroll
                for (int ks = 0; ks < 6; ++ks) c = MFMA16(af[ks], bw1[p][ks], c);
#pragma unroll
                for (int r = 0; r < 4; ++r)
                    vs[r] += fmaxf(c[r] + b1v[p], 0.f) * w2v[p];
            }
#pragma unroll
            for (int mask = 1; mask < 16; mask <<= 1) {
#pragma unroll
                for (int r = 0; r < 4; ++r)
                    vs[r] += __shfl_xor(vs[r], mask);
            }
            if (ln == 0) {
#pragma unroll
                for (int r = 0; r < 4; ++r)
                    s_part[w][mt*16 + lq*4 + r] = vs[r];
            }
        }
    };
    auto Dp = [&](int ch) {   // out write
        const int gbase = (b0 << 11) + baseposl + ch*64;
        if (tid < 64) {
            out[gbase + tid] = s_part[0][tid] + s_part[1][tid]
                             + s_part[2][tid] + s_part[3][tid] + bias2;
        }
    };

    A(0);
    barrier_lds();
#pragma unroll 1
    for (int ch = 0; ch < 4; ++ch) {
        Bp(ch);
        barrier_lds();
        Cp();
        barrier_lds();
        Dp(ch);                      // reads s_part
        if (ch < 3) A(ch + 1);       // writes s_mc/s_te1 — disjoint, overlapped
        barrier_lds();
    }
}

extern "C" void kernel_launch(void* const* d_in, const int* in_sizes, int n_in,
                              void* d_out, int out_size, void* d_ws, size_t ws_size,
                              hipStream_t stream)
{
    const float* x     = (const float*)d_in[0];
    const float* t     = (const float*)d_in[1];
    const float* mtok  = (const float*)d_in[2];
    const float* te_w1 = (const float*)d_in[3];
    const float* te_b1 = (const float*)d_in[4];
    const float* te_w2 = (const float*)d_in[5];
    const float* te_b2 = (const float*)d_in[6];
    const float* fpw   = (const float*)d_in[7];
    const float* fpb   = (const float*)d_in[8];
    const float* bpw   = (const float*)d_in[9];
    const float* bpb   = (const float*)d_in[10];
    const float* fwz   = (const float*)d_in[11];
    const float* fbz   = (const float*)d_in[12];
    const float* fwh   = (const float*)d_in[13];
    const float* fbh   = (const float*)d_in[14];
    const float* bwz   = (const float*)d_in[15];
    const float* bbz   = (const float*)d_in[16];
    const float* bwh   = (const float*)d_in[17];
    const float* bbh   = (const float*)d_in[18];
    const float* w1    = (const float*)d_in[19];
    const float* b1    = (const float*)d_in[20];
    const float* w2    = (const float*)d_in[21];
    const float* b2    = (const float*)d_in[22];

    // per b: h (2 dirs) = 512 KB
    const size_t per_b = 524288ull;
    int Bg = NB;
    while ((size_t)Bg * per_b > ws_size && Bg > 1) Bg >>= 1;
    const int nG = NB / Bg;

    char* ws = (char*)d_ws;
    unsigned short* hf = (unsigned short*)ws;
    unsigned short* hb = hf + (size_t)Bg * NL * 64;

    for (int g = 0; g < nG; ++g) {
        const int b0 = g * Bg;

        scan_fused<<<2 * Bg, 512, 0, stream>>>(
            x, t, mtok, te_w1, te_b1, te_w2, te_b2,
            fpw, fpb, bpw, bpb, fwz, fbz, fwh, fbh, bwz, bbz, bwh, bbh,
            b0, hf, hb);

        head_kernel<<<8 * Bg, 256, 0, stream>>>(
            x, t, te_w1, te_b1, te_w2, te_b2,
            hf, hb, w1, b1, w2, b2, b0, (float*)d_out);
    }
}

// Round 5
// 317.284 us; speedup vs baseline: 1.5269x; 1.5269x over previous
//
#include <hip/hip_runtime.h>
#include <stdint.h>

// Problem constants (B=256, L=2048, H=64, TE=64)
#define NB 256
#define NL 2048

typedef __attribute__((ext_vector_type(8))) short short8;
typedef __attribute__((ext_vector_type(4))) float f32x4;
#define MFMA16(a,b,c) __builtin_amdgcn_mfma_f32_16x16x32_bf16(a,b,c,0,0,0)

// ---------- bf16 helpers ----------
// R16: inp bf16 intermediate, gates in scan (371->334).
// R17: full fusion (prep eliminated) — REGRESSED 484: launch_bounds(512,2)
//      capped VGPR at 128, ~200-reg working set spilled to scratch
//      (FETCH 314MB / WRITE 290MB of spill traffic).
// R18: spill fix — (a) wave w=(mq,nh) owns 2 m-tiles x 2 n-tiles ->
//      per-wave weight frags 144->72 VGPRs; (b) te1 staged via LDS
//      (removes w1v/b1v); (c) launch_bounds(512) only, no forced occ.
// R19: identical resubmit — R18 bench was an infra failure (container),
//      not a kernel verdict.
static __device__ __forceinline__ unsigned short f2bf(float f) {
    union { float f; uint32_t u; } v; v.f = f;
    uint32_t u = v.u;
    uint32_t r = u + 0x7fffu + ((u >> 16) & 1u);
    return (unsigned short)(r >> 16);
}
static __device__ __forceinline__ float bflo(uint32_t u) {
    union { uint32_t u; float f; } v; v.u = u << 16; return v.f;
}
static __device__ __forceinline__ float bfhi(uint32_t u) {
    union { uint32_t u; float f; } v; v.u = u & 0xffff0000u; return v.f;
}
#if __has_builtin(__builtin_amdgcn_cvt_pk_bf16_f32)
typedef __attribute__((ext_vector_type(2))) __bf16 bf16x2_t;
static __device__ __forceinline__ uint32_t pk2(float lo, float hi) {
    union { bf16x2_t v; uint32_t u; } c;
    c.v = __builtin_amdgcn_cvt_pk_bf16_f32(lo, hi);
    return c.u;
}
static __device__ __forceinline__ unsigned short bf1(float v) {
    union { bf16x2_t v; uint32_t u; } c;
    c.v = __builtin_amdgcn_cvt_pk_bf16_f32(v, v);
    return (unsigned short)(c.u & 0xffffu);
}
#else
static __device__ __forceinline__ uint32_t pk2(float lo, float hi) {
    return ((uint32_t)f2bf(hi) << 16) | (uint32_t)f2bf(lo);
}
static __device__ __forceinline__ unsigned short bf1(float v) { return f2bf(v); }
#endif
static __device__ __forceinline__ short8 frag8(const float* p) {
    short8 r;
#pragma unroll
    for (int j = 0; j < 8; ++j) r[j] = (short)f2bf(p[j]);
    return r;
}

// LDS-only barrier: global stores/loads stay in flight across it.
static __device__ __forceinline__ void barrier_lds() {
    asm volatile("s_waitcnt lgkmcnt(0)" ::: "memory");
    __builtin_amdgcn_s_barrier();
}

// =====================================================================
// kernel 1: fused inp-gen + gates + chunked scan.
// 512 thr = 8 waves. Scan: lane = h (64), wave q owns 16-l chunk.
// Gen GEMMs: wave w=(mq=w>>1, nh=w&1) owns m-tiles {2mq,2mq+1} and
// n-tiles {2nh,2nh+1}. Pipeline per segment (3 barriers):
//   alpha { OUT(i-1) | GATES(i) | stageTE1(i+1) }
//   beta  { scanAB(i) | G1(i+1) }
//   gamma { carry(i) | G2(i+1) | prefetch t/x(i+2) }
// All fragment orders/roundings identical to R16 -> bitwise-identical h.
// =====================================================================
#define SSTR 129

__global__ __launch_bounds__(512) void scan_fused(
    const float* __restrict__ x, const float* __restrict__ t,
    const float* __restrict__ mtok,
    const float* __restrict__ te_w1, const float* __restrict__ te_b1,
    const float* __restrict__ te_w2, const float* __restrict__ te_b2,
    const float* __restrict__ fpw, const float* __restrict__ fpb,
    const float* __restrict__ bpw, const float* __restrict__ bpb,
    const float* __restrict__ fwz, const float* __restrict__ fbz,
    const float* __restrict__ fwh, const float* __restrict__ fbh,
    const float* __restrict__ bwz, const float* __restrict__ bbz,
    const float* __restrict__ bwh, const float* __restrict__ bbh,
    int b0,
    unsigned short* __restrict__ hf, unsigned short* __restrict__ hb)
{
    __shared__ __align__(16) unsigned short s_te1[128*72];   // 18432 B
    __shared__ __align__(16) unsigned short s_tenc[128*72];  // 18432 B
    __shared__ __align__(16) unsigned short s_inp[128*72];   // 18432 B
    __shared__ uint32_t s_seg[64*SSTR];                      // 33024 B
    __shared__ float s_A[8][65], s_B[8][65];                 //  4160 B
    __shared__ float s_H[64];                                //   256 B

    const int rl  = blockIdx.x >> 1;
    const int dir = blockIdx.x & 1;
    const int tid = threadIdx.x;
    const int h   = tid & 63;     // lane
    const int q   = tid >> 6;     // wave 0..7
    const int lq  = h >> 4;
    const int ln  = h & 15;
    const int mq  = q >> 1;       // m-tile pair owner (0..3)
    const int nh  = q & 1;        // n-tile pair owner (0..1)

    const int gx = (b0 + rl) << 11;     // global l base for this b
    unsigned short* out = (dir ? hb : hf) + (size_t)rl * NL * 64;

    // te1 staging coords (all 512 threads)
    const int tpos = tid & 127;
    const int tk0  = (tid >> 7) * 16;

    // ---- weights (persistent regs, nt-split: only this wave's 2 n-tiles) ----
    short8 bte[2][2];
    float bite[2];
#pragma unroll
    for (int ni = 0; ni < 2; ++ni) {
        const int nt = nh*2 + ni;
        const float* row = te_w2 + (nt*16 + ln)*64;
#pragma unroll
        for (int ks = 0; ks < 2; ++ks) bte[ni][ks] = frag8(row + lq*8 + ks*32);
        bite[ni] = te_b2[nt*16 + ln];
    }
    const float* PW = dir ? bpw : fpw;
    const float* PB = dir ? bpb : fpb;
    short8 bpj[2][3];
    float bipj[2];
#pragma unroll
    for (int ni = 0; ni < 2; ++ni) {
        const int nt = nh*2 + ni;
        const float* row = PW + (nt*16 + ln)*67;
#pragma unroll
        for (int ks = 0; ks < 2; ++ks) {
            float tmp[8];
#pragma unroll
            for (int j = 0; j < 8; ++j) tmp[j] = row[3 + lq*8 + ks*32 + j];
            bpj[ni][ks] = frag8(tmp);
        }
        {
            float tmp[8];
#pragma unroll
            for (int j = 0; j < 8; ++j) tmp[j] = (lq == 0 && j < 3) ? row[j] : 0.f;
            bpj[ni][2] = frag8(tmp);
        }
        bipj[ni] = PB[nt*16 + ln];
    }
    const float* WZ = dir ? bwz : fwz;
    const float* WH = dir ? bwh : fwh;
    const float* BZ = dir ? bbz : fbz;
    const float* BH = dir ? bbh : fbh;
    short8 bz[2][2], bh[2][2];
    float biz[2], bih[2];
#pragma unroll
    for (int ni = 0; ni < 2; ++ni) {
        const int nt = nh*2 + ni;
        const float* rz = WZ + (nt*16 + ln)*64;
        const float* rh = WH + (nt*16 + ln)*64;
#pragma unroll
        for (int ks = 0; ks < 2; ++ks) {
            bz[ni][ks] = frag8(rz + lq*8 + ks*32);
            bh[ni][ks] = frag8(rh + lq*8 + ks*32);
        }
        biz[ni] = BZ[nt*16 + ln];
        bih[ni] = BH[nt*16 + ln];
    }
    const float mt0 = mtok[0], mt1 = mtok[1];

    // x prefetch registers (named per m-tile; compile-time indexed)
    float xr0_[2], xr1_[2], xmc_[2];
    float tvp = 0.f;

    // ---- phase lambdas ----
    auto TE = [&](float tv) {   // stage te1[l][k] for one segment (512 thr)
        uint32_t* dst = (uint32_t*)(s_te1 + tpos*72 + tk0);
#pragma unroll
        for (int kk = 0; kk < 16; kk += 2) {
            float v0 = fmaxf(fmaf(tv, te_w1[tk0+kk],   te_b1[tk0+kk]),   0.f);
            float v1 = fmaxf(fmaf(tv, te_w1[tk0+kk+1], te_b1[tk0+kk+1]), 0.f);
            dst[kk >> 1] = pk2(v0, v1);
        }
    };
    auto PFX = [&](int sseg) {  // prefetch x rows for this wave's 2 m-tiles
        if (lq == 0) {
#pragma unroll
            for (int mi = 0; mi < 2; ++mi) {
                const float* xp = x + (size_t)(gx + sseg*128 + (mq*2+mi)*16 + ln)*3;
                xr0_[mi] = xp[0]; xr1_[mi] = xp[1]; xmc_[mi] = xp[2];
            }
        }
    };
    auto G1 = [&]() {           // s_te1 -> tenc GEMM -> s_tenc
#pragma unroll
        for (int mi = 0; mi < 2; ++mi) {
            const int mrow = (mq*2+mi)*16 + ln;
            const short8 a0 = *(const short8*)(s_te1 + mrow*72 + lq*8);
            const short8 a1 = *(const short8*)(s_te1 + mrow*72 + lq*8 + 32);
#pragma unroll
            for (int ni = 0; ni < 2; ++ni) {
                f32x4 c = {0.f, 0.f, 0.f, 0.f};
                c = MFMA16(a0, bte[ni][0], c);
                c = MFMA16(a1, bte[ni][1], c);
                const int o = (nh*2+ni)*16 + ln;
#pragma unroll
                for (int r = 0; r < 4; ++r)
                    s_tenc[((mq*2+mi)*16 + lq*4 + r)*72 + o] = bf1(c[r] + bite[ni]);
            }
        }
    };
    auto G2 = [&]() {           // s_tenc + in-reg x3 -> s_inp
#pragma unroll
        for (int mi = 0; mi < 2; ++mi) {
            const int mrow = (mq*2+mi)*16 + ln;
            const short8 a0 = *(const short8*)(s_tenc + mrow*72 + lq*8);
            const short8 a1 = *(const short8*)(s_tenc + mrow*72 + lq*8 + 32);
            short8 a2 = {0,0,0,0,0,0,0,0};
            if (lq == 0) {
                const float mc  = xmc_[mi];
                const float x0m = (mc == 0.f) ? mt0 : xr0_[mi];
                const float x1m = (mc == 0.f) ? mt1 : xr1_[mi];
                a2[0] = (short)bf1(x0m);
                a2[1] = (short)bf1(x1m);
                a2[2] = (short)bf1(mc);
            }
#pragma unroll
            for (int ni = 0; ni < 2; ++ni) {
                f32x4 c = {0.f, 0.f, 0.f, 0.f};
                c = MFMA16(a0, bpj[ni][0], c);
                c = MFMA16(a1, bpj[ni][1], c);
                c = MFMA16(a2, bpj[ni][2], c);
                const int o = (nh*2+ni)*16 + ln;
#pragma unroll
                for (int r = 0; r < 4; ++r)
                    s_inp[((mq*2+mi)*16 + lq*4 + r)*72 + o] = bf1(c[r] + bipj[ni]);
            }
        }
    };
    auto GATES = [&]() {        // s_inp -> gates -> s_seg
#pragma unroll
        for (int mi = 0; mi < 2; ++mi) {
            const int mrow = (mq*2+mi)*16 + ln;
            const short8 a0 = *(const short8*)(s_inp + mrow*72 + lq*8);
            const short8 a1 = *(const short8*)(s_inp + mrow*72 + lq*8 + 32);
#pragma unroll
            for (int ni = 0; ni < 2; ++ni) {
                f32x4 cz  = {0.f, 0.f, 0.f, 0.f};
                f32x4 ch2 = {0.f, 0.f, 0.f, 0.f};
                cz  = MFMA16(a0, bz[ni][0], cz);
                cz  = MFMA16(a1, bz[ni][1], cz);
                ch2 = MFMA16(a0, bh[ni][0], ch2);
                ch2 = MFMA16(a1, bh[ni][1], ch2);
                const int hcol = (nh*2+ni)*16 + ln;
#pragma unroll
                for (int r = 0; r < 4; ++r) {
                    const float az = cz[r]  + biz[ni];
                    const float ah = ch2[r] + bih[ni];
                    const float z  = __builtin_amdgcn_rcpf(1.f + __expf(-az));
                    const float cc = fminf(fmaxf(ah, -15.f), 15.f);
                    const float e2 = __expf(2.f * cc);
                    const float th = 1.f - 2.f * __builtin_amdgcn_rcpf(e2 + 1.f);
                    s_seg[hcol*SSTR + (mq*2+mi)*16 + lq*4 + r] = pk2(1.f - z, z * th);
                }
            }
        }
    };

    if (tid < 64) s_H[tid] = 0.f;

    // ---- prologue: fill pipeline for segment s0 ----
    const int s0 = dir ? 15 : 0;
    const int s1 = dir ? 14 : 1;
    TE(t[gx + s0*128 + tpos]);
    barrier_lds();
    G1();                      // seg s0 -> s_tenc
    barrier_lds();
    PFX(s0);
    G2();                      // seg s0 -> s_inp
    tvp = t[gx + s1*128 + tpos];
    PFX(s1);
    barrier_lds();

    uint32_t regs[16];
    int l0p = 0;

#pragma unroll 1
    for (int si = 0; si < 16; ++si) {
        const int s = dir ? (15 - si) : si;
        // ---- alpha: OUT(prev) + GATES(cur) + TE(next) ----
        if (si > 0) {
            float hv = s_A[q][h];     // Hin written in-place by carry
#pragma unroll
            for (int i = 0; i < 16; ++i) {
                const int g = q*16 + i;
                const int xx = dir ? (127 - g) : g;
                out[(size_t)(l0p + xx)*64 + h] = bf1(hv);
                hv = fmaf(bflo(regs[i]), hv, bfhi(regs[i]));
            }
        }
        GATES();
        if (si < 15) TE(tvp);
        barrier_lds();
        // ---- beta: scanAB(cur) + G1(next) ----
        {
            float A = 1.f, Bc = 0.f;
#pragma unroll
            for (int i = 0; i < 16; ++i) {
                const int g = q*16 + i;
                const int xx = dir ? (127 - g) : g;
                const uint32_t uab = s_seg[h*SSTR + xx];
                regs[i] = uab;
                Bc = fmaf(bflo(uab), Bc, bfhi(uab));
                A *= bflo(uab);
            }
            s_A[q][h] = A; s_B[q][h] = Bc;
        }
        if (si < 15) G1();
        barrier_lds();
        // ---- gamma: carry(cur) + G2(next) + prefetch(next2) ----
        if (tid < 64) {
            float H = s_H[tid];
#pragma unroll
            for (int qq = 0; qq < 8; ++qq) {
                const float a = s_A[qq][tid], b = s_B[qq][tid];
                s_A[qq][tid] = H;          // in-place Hin
                H = fmaf(a, H, b);
            }
            s_H[tid] = H;
        }
        if (si < 15) {
            G2();
            if (si < 14) {
                const int s2 = dir ? (13 - si) : (si + 2);
                tvp = t[gx + s2*128 + tpos];
                PFX(s2);
            }
        }
        barrier_lds();
        l0p = s * 128;
    }
    // ---- epilogue: OUT(last) ----
    {
        float hv = s_A[q][h];
#pragma unroll
        for (int i = 0; i < 16; ++i) {
            const int g = q*16 + i;
            const int xx = dir ? (127 - g) : g;
            out[(size_t)(l0p + xx)*64 + h] = bf1(hv);
            hv = fmaf(bflo(regs[i]), hv, bfhi(regs[i]));
        }
    }
}

// =====================================================================
// kernel 2: MFMA head — unchanged from R15/R16.
// =====================================================================
__global__ __launch_bounds__(256, 3) void head_kernel(
    const float* __restrict__ x, const float* __restrict__ t,
    const float* __restrict__ te_w1, const float* __restrict__ te_b1,
    const float* __restrict__ te_w2, const float* __restrict__ te_b2,
    const unsigned short* __restrict__ hf, const unsigned short* __restrict__ hb,
    const float* __restrict__ w1, const float* __restrict__ b1,
    const float* __restrict__ w2, const float* __restrict__ b2,
    int b0,
    float* __restrict__ out)
{
    __shared__ __align__(16) unsigned short s_a[64*200];   // 25600 B
    __shared__ __align__(16) unsigned short s_te1[64*72];  //  9216 B
    __shared__ float s_part[4][64];                        //  1024 B
    __shared__ float s_mc[64];                             //   256 B

    const int tid = threadIdx.x;
    const int w   = tid >> 6;
    const int l   = tid & 63;
    const int lq  = l >> 4;
    const int ln  = l & 15;

    short8 bw1[2][6];
    float b1v[2], w2v[2];
#pragma unroll
    for (int p = 0; p < 2; ++p) {
        const int o = (2*w + p)*16 + ln;
        const float* row = w1 + o*192;
#pragma unroll
        for (int ks = 0; ks < 6; ++ks) bw1[p][ks] = frag8(row + lq*8 + ks*32);
        b1v[p] = b1[o];
        w2v[p] = w2[o];
    }
    short8 bte[2];
    {
        const float* row = te_w2 + (w*16 + ln)*64;
#pragma unroll
        for (int ks = 0; ks < 2; ++ks) bte[ks] = frag8(row + lq*8 + ks*32);
    }
    const float bias_te = te_b2[w*16 + ln];
    const float bias2 = b2[0];

    const int baseposl = blockIdx.x * 256;

    auto A = [&](int ch) {    // mc + te1 staging
        const int gbase = (b0 << 11) + baseposl + ch*64;
        if (tid < 64) s_mc[tid] = x[(size_t)(gbase + tid)*3 + 2];
        const int pos = tid & 63;
        const float tv = t[gbase + pos];
        const int k0 = (tid >> 6) * 16;
        uint32_t* dst = (uint32_t*)(s_te1 + pos*72 + k0);
#pragma unroll
        for (int kk = 0; kk < 16; kk += 2) {
            float v0 = fmaxf(fmaf(tv, te_w1[k0+kk],   te_b1[k0+kk]),   0.f);
            float v1 = fmaxf(fmaf(tv, te_w1[k0+kk+1], te_b1[k0+kk+1]), 0.f);
            dst[kk >> 1] = pk2(v0, v1);
        }
    };
    auto Bp = [&](int ch) {   // uint4 gather + tenc GEMM (disjoint s_a cols)
        const int chbase = baseposl + ch*64;
        const int ll0 = chbase & 2047;
        const int bl  = chbase >> 11;
        const size_t rowbase = (size_t)bl * NL * 64;
#pragma unroll
        for (int rep = 0; rep < 4; ++rep) {
            const int idx = rep*256 + tid;
            const int seg = idx >> 9;
            const int row = (idx >> 3) & 63;
            const int c   = idx & 7;
            const bool unm = s_mc[row] > 0.f;
            const uint4* src = (seg == 0)
                ? (const uint4*)(hf + rowbase + (size_t)(unm ? (ll0+row) : (NL-1))*64)
                : (const uint4*)(hb + rowbase + (size_t)(unm ? (ll0+row) : 0)*64);
            ((uint4*)s_a)[row*25 + seg*8 + c] = src[c];
        }
        const int o = w*16 + ln;
#pragma unroll
        for (int mt = 0; mt < 4; ++mt) {
            f32x4 c = {0.f, 0.f, 0.f, 0.f};
#pragma unroll
            for (int ks = 0; ks < 2; ++ks) {
                const short8 a = *(const short8*)(s_te1 + (mt*16+ln)*72 + lq*8 + ks*32);
                c = MFMA16(a, bte[ks], c);
            }
#pragma unroll
            for (int r = 0; r < 4; ++r) {
                const int m = mt*16 + lq*4 + r;
                s_a[m*200 + 128 + o] = bf1(c[r] + bias_te);
            }
        }
    };
    auto Cp = [&]() {         // GEMM1 + relu*w2 + quad shuffle-reduce
#pragma unroll
        for (int mt = 0; mt < 4; ++mt) {
            short8 af[6];
#pragma unroll
            for (int ks = 0; ks < 6; ++ks)
                af[ks] = *(const short8*)(s_a + (mt*16+ln)*200 + lq*8 + ks*32);
            float vs[4] = {0.f, 0.f, 0.f, 0.f};
#pragma unroll
            for (int p = 0; p < 2; ++p) {
                f32x4 c = {0.f, 0.f, 0.f, 0.f};
#pragma unroll
                for (int ks = 0; ks < 6; ++ks) c = MFMA16(af[ks], bw1[p][ks], c);
#pragma unroll
                for (int r = 0; r < 4; ++r)
                    vs[r] += fmaxf(c[r] + b1v[p], 0.f) * w2v[p];
            }
#pragma unroll
            for (int mask = 1; mask < 16; mask <<= 1) {
#pragma unroll
                for (int r = 0; r < 4; ++r)
                    vs[r] += __shfl_xor(vs[r], mask);
            }
            if (ln == 0) {
#pragma unroll
                for (int r = 0; r < 4; ++r)
                    s_part[w][mt*16 + lq*4 + r] = vs[r];
            }
        }
    };
    auto Dp = [&](int ch) {   // out write
        const int gbase = (b0 << 11) + baseposl + ch*64;
        if (tid < 64) {
            out[gbase + tid] = s_part[0][tid] + s_part[1][tid]
                             + s_part[2][tid] + s_part[3][tid] + bias2;
        }
    };

    A(0);
    barrier_lds();
#pragma unroll 1
    for (int ch = 0; ch < 4; ++ch) {
        Bp(ch);
        barrier_lds();
        Cp();
        barrier_lds();
        Dp(ch);                      // reads s_part
        if (ch < 3) A(ch + 1);       // writes s_mc/s_te1 — disjoint, overlapped
        barrier_lds();
    }
}

extern "C" void kernel_launch(void* const* d_in, const int* in_sizes, int n_in,
                              void* d_out, int out_size, void* d_ws, size_t ws_size,
                              hipStream_t stream)
{
    const float* x     = (const float*)d_in[0];
    const float* t     = (const float*)d_in[1];
    const float* mtok  = (const float*)d_in[2];
    const float* te_w1 = (const float*)d_in[3];
    const float* te_b1 = (const float*)d_in[4];
    const float* te_w2 = (const float*)d_in[5];
    const float* te_b2 = (const float*)d_in[6];
    const float* fpw   = (const float*)d_in[7];
    const float* fpb   = (const float*)d_in[8];
    const float* bpw   = (const float*)d_in[9];
    const float* bpb   = (const float*)d_in[10];
    const float* fwz   = (const float*)d_in[11];
    const float* fbz   = (const float*)d_in[12];
    const float* fwh   = (const float*)d_in[13];
    const float* fbh   = (const float*)d_in[14];
    const float* bwz   = (const float*)d_in[15];
    const float* bbz   = (const float*)d_in[16];
    const float* bwh   = (const float*)d_in[17];
    const float* bbh   = (const float*)d_in[18];
    const float* w1    = (const float*)d_in[19];
    const float* b1    = (const float*)d_in[20];
    const float* w2    = (const float*)d_in[21];
    const float* b2    = (const float*)d_in[22];

    // per b: h (2 dirs) = 512 KB
    const size_t per_b = 524288ull;
    int Bg = NB;
    while ((size_t)Bg * per_b > ws_size && Bg > 1) Bg >>= 1;
    const int nG = NB / Bg;

    char* ws = (char*)d_ws;
    unsigned short* hf = (unsigned short*)ws;
    unsigned short* hb = hf + (size_t)Bg * NL * 64;

    for (int g = 0; g < nG; ++g) {
        const int b0 = g * Bg;

        scan_fused<<<2 * Bg, 512, 0, stream>>>(
            x, t, mtok, te_w1, te_b1, te_w2, te_b2,
            fpw, fpb, bpw, bpb, fwz, fbz, fwh, fbh, bwz, bbz, bwh, bbh,
            b0, hf, hb);

        head_kernel<<<8 * Bg, 256, 0, stream>>>(
            x, t, te_w1, te_b1, te_w2, te_b2,
            hf, hb, w1, b1, w2, b2, b0, (float*)d_out);
    }
}